// Round 14
// baseline (149.947 us; speedup 1.0000x reference)
//
#include <hip/hip_runtime.h>
#include <hip/hip_bf16.h>

// Problem dims (fixed by reference setup)
#define B_   16
#define N_   8
#define C_   512
#define D_   768
#define HH   64
#define WW   64
#define HW   4096          // 64*64 pixels per batch

typedef __bf16 bf16;
typedef __attribute__((ext_vector_type(8))) __bf16 bf16x8;
typedef __attribute__((ext_vector_type(4))) __bf16 bf16x4;
typedef __attribute__((ext_vector_type(4))) float  f32x4;

// ---------------------------------------------------------------------------
// K_pre (single launch) — unchanged from R12/R13.
// Blocks 0..127  : (b,n): Q in-register -> Ql LDS; Qkf in MFMA-fragment order.
// Blocks 128..639: W2f = wo_w·wv_w in fragment order; b2.
__global__ __launch_bounds__(512) void k_pre(const float* __restrict__ se,
                                             const float* __restrict__ weights,
                                             const float* __restrict__ wq_w,
                                             const float* __restrict__ wq_b,
                                             const float* __restrict__ wk_w,
                                             const float* __restrict__ wo_w,
                                             const float* __restrict__ wv_w,
                                             const float* __restrict__ wv_b,
                                             bf16* __restrict__ Qkf,
                                             bf16* __restrict__ W2f,
                                             float* __restrict__ b2) {
    __shared__ __align__(16) unsigned char smem[12288];
    int tid = threadIdx.x;
    int blk = blockIdx.x;
    if (blk < 128) {
        int b = blk >> 3, n = blk & 7;
        float* we = (float*)smem;                     // [768]
        float* Ql = (float*)(smem + 3072);            // [512]
        float wt = weights[n];
        const float* se_row = se + (size_t)(b * N_ + n) * D_;
        for (int i = tid; i < D_; i += 512) we[i] = se_row[i] * wt;
        __syncthreads();
        int wid = tid >> 6, lane = tid & 63;
        f32x4 wer[3];
        #pragma unroll
        for (int k = 0; k < 3; ++k)
            wer[k] = *(const f32x4*)(we + k * 256 + lane * 4);
        int c0 = wid * 64;
        #pragma unroll 2
        for (int cc = 0; cc < 64; ++cc) {
            int c = c0 + cc;
            const float* row = wq_w + (size_t)c * D_ + lane * 4;
            float dot = 0.f;
            #pragma unroll
            for (int k = 0; k < 3; ++k) {
                f32x4 v = *(const f32x4*)(row + k * 256);
                dot += v[0]*wer[k][0] + v[1]*wer[k][1]
                     + v[2]*wer[k][2] + v[3]*wer[k][3];
            }
            #pragma unroll
            for (int off = 1; off <= 32; off <<= 1) dot += __shfl_xor(dot, off);
            if (lane == 0) Ql[c] = dot + wq_b[c];
        }
        __syncthreads();
        int m = tid;
        float a0 = 0.f, a1 = 0.f, a2 = 0.f, a3 = 0.f;
        #pragma unroll 2
        for (int o = 0; o < C_; o += 4) {
            a0 = fmaf(Ql[o + 0], wk_w[(size_t)(o + 0) * C_ + m], a0);
            a1 = fmaf(Ql[o + 1], wk_w[(size_t)(o + 1) * C_ + m], a1);
            a2 = fmaf(Ql[o + 2], wk_w[(size_t)(o + 2) * C_ + m], a2);
            a3 = fmaf(Ql[o + 3], wk_w[(size_t)(o + 3) * C_ + m], a3);
        }
        float val = ((a0 + a1) + (a2 + a3)) * 3.6084391824351615e-2f;
        int t = m >> 5, sl = (m >> 3) & 3, el = m & 7;
        size_t qb = (size_t)b * 8192 + (size_t)t * 512;
        Qkf[qb + (size_t)(n | (sl << 4)) * 8 + el]       = (bf16)val;
        Qkf[qb + (size_t)((n + 8) | (sl << 4)) * 8 + el] = (bf16)0.f;
    } else {
        int bb = blk - 128;                           // 0..511
        int og = bb >> 3, cc = bb & 7;
        int cl = tid & 63, kq = tid >> 6;
        int kqq = kq & 3;
        int khalf = kq >> 2;
        int c  = cc * 64 + cl;
        const float* wo = wo_w + (size_t)og * 8 * C_;
        float a[8] = {};
        #pragma unroll 4
        for (int i = 0; i < 64; ++i) {
            int k = kqq * 128 + khalf * 64 + i;
            float v = wv_w[(size_t)k * C_ + c];
            #pragma unroll
            for (int j = 0; j < 8; ++j)
                a[j] = fmaf(wo[(size_t)j * C_ + k], v, a[j]);
        }
        float (*part)[8][64] = (float(*)[8][64])smem;
        #pragma unroll
        for (int j = 0; j < 8; ++j) {
            if (khalf) part[kqq][j][cl] = a[j];
        }
        __syncthreads();
        if (khalf == 0) {
            #pragma unroll
            for (int j = 0; j < 8; ++j) part[kqq][j][cl] += a[j];
        }
        __syncthreads();
        if (kq == 0) {
            int t  = c >> 5;
            int ln = (((c >> 3) & 3) << 4);
            int el = c & 7;
            #pragma unroll
            for (int j = 0; j < 8; ++j) {
                float s = part[0][j][cl] + part[1][j][cl]
                        + part[2][j][cl] + part[3][j][cl];
                int o = og * 8 + j;
                W2f[(size_t)t * 16384 + (o >> 7) * 4096 + ((o >> 4) & 7) * 512
                    + (size_t)((o & 15) | ln) * 8 + el] = (bf16)s;
            }
        }
        if (cc == 0 && tid < 8) {
            float sb = 0.f;
            const float* rr = wo_w + (size_t)(og * 8 + tid) * C_;
            #pragma unroll 4
            for (int m = 0; m < C_; ++m) sb = fmaf(rr[m], wv_b[m], sb);
            b2[og * 8 + tid] = sb;
        }
    }
}

// ---------------------------------------------------------------------------
// K2 (fused v8, 64-px panel / 2 blocks per CU): per block (b, pt=h-row):
//   Bp[64 px][512 c] bf16 (64KB, swz, persistent; residual source).
//   8 waves; wave wid owns o-range [wid*64, wid*64+64); acc[4][4] (64 VGPR).
//   PHASE 1: bulk-stage Bp (2-deep reg pipeline); ONE barrier.
//   PHASE 2: 16 tiles {A-frags from L2 fragment-order W2f, 4 ds_read, 16 MFMA},
//            zero barriers. 2 blocks/CU overlap staging with compute (TLP).
//   Softmax (wave 0) over the h-row; epilogue residual from Bp.
__global__ __launch_bounds__(512, 4) void k_fused(const float* __restrict__ x,
                                                  const bf16* __restrict__ W2f,
                                                  const float* __restrict__ b2,
                                                  const float* __restrict__ wo_b,
                                                  const bf16* __restrict__ Qkf,
                                                  float* __restrict__ out) {
    // XCD swizzle (1024 % 8 == 0 -> bijective); each XCD gets 2 full batches
    int id = blockIdx.x;
    int job = (id & 7) * 128 + (id >> 3);         // 0..1023
    int b = job >> 6, pt = job & 63;
    int p0 = pt * 64;                             // one complete h-row

    __shared__ __align__(128) unsigned char Bp[65536]; // [64 px][512 c] bf16 swz
    __shared__ float s_lds[64];

    int tid = threadIdx.x;
    int wid = tid >> 6, lane = tid & 63;

    int pg = tid & 63, cg = tid >> 6;             // B-stage: pixel, c-octet (0..7)
    int fB = pg << 4;                             // full-slot swizzle

    f32x4 acc[4][4] = {};
    f32x4 acc_q[4] = {};

    const float* xb = x + (size_t)b * C_ * HW + p0 + pg;
    const bf16* Wb  = W2f + (wid >> 1) * 4096 + (wid & 1) * 2048 + (size_t)lane * 8;
    const bf16* Qb  = Qkf + (size_t)b * 8192 + (size_t)lane * 8;

#define IB(T, BV)                                                             \
    { _Pragma("unroll")                                                       \
      for (int i = 0; i < 8; ++i)                                            \
          BV[i] = xb[(size_t)((T)*64 + cg*8 + i) * HW]; }

#define SW(T, BV)                                                             \
    { bf16x8 bw;                                                              \
      _Pragma("unroll")                                                       \
      for (int i = 0; i < 8; ++i) bw[i] = (bf16)BV[i];                        \
      *(bf16x8*)(&Bp[pg*1024 + ((((T)*128) + cg*16) ^ fB)]) = bw; }

#define IA(T)                                                                 \
    { _Pragma("unroll")                                                       \
      for (int i = 0; i < 4; ++i)                                            \
          av[i] = *(const bf16x8*)(Wb + (size_t)(T)*16384 + i*512);           \
      if (wid == 0) aq = *(const bf16x8*)(Qb + (size_t)(T)*512); }

#define MT(T)                                                                 \
    { int kb = (T)*64 + ((lane>>4)<<4);                                       \
      bf16x8 bbf[4];                                                          \
      _Pragma("unroll")                                                       \
      for (int j = 0; j < 4; ++j) {                                          \
          int row = j*16 + (lane&15);                                         \
          bbf[j] = *(const bf16x8*)(&Bp[row*1024 + (kb ^ (row<<4))]);         \
      }                                                                       \
      __builtin_amdgcn_s_setprio(1);                                          \
      _Pragma("unroll")                                                       \
      for (int i = 0; i < 4; ++i)                                            \
          _Pragma("unroll")                                                   \
          for (int j = 0; j < 4; ++j)                                        \
              acc[i][j] = __builtin_amdgcn_mfma_f32_16x16x32_bf16(            \
                              av[i], bbf[j], acc[i][j], 0, 0, 0);             \
      if (wid == 0) {                                                         \
          _Pragma("unroll")                                                   \
          for (int j = 0; j < 4; ++j)                                        \
              acc_q[j] = __builtin_amdgcn_mfma_f32_16x16x32_bf16(             \
                             aq, bbf[j], acc_q[j], 0, 0, 0);                  \
      }                                                                       \
      __builtin_amdgcn_s_setprio(0); }

    // ---- PHASE 1: bulk-stage Bp (8 batches of 64 c), 2-deep pipeline ----
    {
        float v0[8], v1[8];
        IB(0, v0); IB(1, v1);
        SW(0, v0); IB(2, v0);
        SW(1, v1); IB(3, v1);
        SW(2, v0); IB(4, v0);
        SW(3, v1); IB(5, v1);
        SW(4, v0); IB(6, v0);
        SW(5, v1); IB(7, v1);
        SW(6, v0); SW(7, v1);
    }
    __syncthreads();                              // Bp fully staged (only barrier)

    // ---- PHASE 2: 16 tiles, NO barriers ----
    {
        bf16x8 av[4];
        bf16x8 aq = {};
        #pragma unroll 1
        for (int t = 0; t < 16; ++t) {
            IA(t);
            MT(t);
        }
    }

    // ---- softmax over w (the 64-px row) on wave 0 ----
    if (wid == 0) {
        float sm[4];
        #pragma unroll
        for (int r = 0; r < 4; ++r) {
            float m = fmaxf(fmaxf(acc_q[0][r], acc_q[1][r]),
                            fmaxf(acc_q[2][r], acc_q[3][r]));
            #pragma unroll
            for (int off = 1; off <= 8; off <<= 1) m = fmaxf(m, __shfl_xor(m, off));
            float s = 0.f;
            #pragma unroll
            for (int j = 0; j < 4; ++j) { acc_q[j][r] = __expf(acc_q[j][r] - m); s += acc_q[j][r]; }
            #pragma unroll
            for (int off = 1; off <= 8; off <<= 1) s += __shfl_xor(s, off);
            sm[r] = s;
        }
        f32x4 rcp;
        #pragma unroll
        for (int r = 0; r < 4; ++r) rcp[r] = 1.f / sm[r];
        #pragma unroll
        for (int j = 0; j < 4; ++j) {
            float sp = acc_q[j][0]*rcp[0] + acc_q[j][1]*rcp[1]
                     + acc_q[j][2]*rcp[2] + acc_q[j][3]*rcp[3];
            sp += __shfl_xor(sp, 16);             // add the other n-quad
            if (lane < 16) s_lds[j*16 + lane] = sp;
        }
    }
    __syncthreads();

    // ---- epilogue: out = bf16(x) + wo_b + s*(acc + b2); residual from Bp ----
    int r4 = (lane >> 4) << 2;
    int cl = lane & 15;
    #pragma unroll
    for (int j = 0; j < 4; ++j) {
        int pl = j * 16 + cl;
        float sv = s_lds[pl];
        int fBp = pl << 4;
        #pragma unroll
        for (int i = 0; i < 4; ++i) {
            int ob = wid * 64 + i * 16 + r4;
            f32x4 b2v = *(const f32x4*)(b2 + ob);
            f32x4 wbv = *(const f32x4*)(wo_b + ob);
            bf16x4 rx = *(const bf16x4*)(&Bp[pl*1024 + ((ob*2) ^ fBp)]);
            #pragma unroll
            for (int r = 0; r < 4; ++r) {
                size_t gi = ((size_t)b * C_ + ob + r) * HW + p0 + pl;
                out[gi] = (float)rx[r] + wbv[r] + sv * (acc[i][j][r] + b2v[r]);
            }
        }
    }
#undef IB
#undef SW
#undef IA
#undef MT
}

// ---------------------------------------------------------------------------
extern "C" void kernel_launch(void* const* d_in, const int* in_sizes, int n_in,
                              void* d_out, int out_size, void* d_ws, size_t ws_size,
                              hipStream_t stream) {
    const float* x    = (const float*)d_in[0];
    const float* se   = (const float*)d_in[1];
    const float* wts  = (const float*)d_in[2];
    const float* wq_w = (const float*)d_in[3];
    const float* wq_b = (const float*)d_in[4];
    const float* wk_w = (const float*)d_in[5];
    // d_in[6] = wk_b: constant over softmax axis -> cancels, unused
    const float* wv_w = (const float*)d_in[7];
    const float* wv_b = (const float*)d_in[8];
    const float* wo_w = (const float*)d_in[9];
    const float* wo_b = (const float*)d_in[10];
    float* out = (float*)d_out;

    // workspace layout (<1MB)
    char* ws = (char*)d_ws;
    bf16*  Qkf = (bf16*) (ws + 0);          // 256KB [16 b][16 t][64 lane][8] frag-order
    bf16*  W2f = (bf16*) (ws + 262144);     // 512KB [16 t][4 wm][8 i][64 lane][8]
    float* b2  = (float*)(ws + 786432);     // 2KB

    k_pre   <<<dim3(640),  dim3(512), 0, stream>>>(se, wts, wq_w, wq_b, wk_w,
                                                   wo_w, wv_w, wv_b, Qkf, W2f, b2);
    k_fused <<<dim3(1024), dim3(512), 0, stream>>>(x, W2f, b2, wo_b, Qkf, out);
}

// Round 15
// 138.646 us; speedup vs baseline: 1.0815x; 1.0815x over previous
//
#include <hip/hip_runtime.h>
#include <hip/hip_bf16.h>

// Problem dims (fixed by reference setup)
#define B_   16
#define N_   8
#define C_   512
#define D_   768
#define HH   64
#define WW   64
#define HW   4096          // 64*64 pixels per batch

typedef __bf16 bf16;
typedef __attribute__((ext_vector_type(8))) __bf16 bf16x8;
typedef __attribute__((ext_vector_type(4))) __bf16 bf16x4;
typedef __attribute__((ext_vector_type(4))) float  f32x4;

// ---------------------------------------------------------------------------
// K_w: blocks 0..95: LDS-tiled transpose wq_w(512x768) -> wqT(768x512).
//      blocks 96..607: W2f[frag(o,c)] = wo_w[o,:]·wv_w[:,c] (bf16, MFMA
//      fragment order), (8 o x 64 c) per block, K split over 4 waves + LDS
//      reduce; b2[o] on c-chunk-0 blocks.
__global__ __launch_bounds__(256) void k_w(const float* __restrict__ wq_w,
                                           const float* __restrict__ wo_w,
                                           const float* __restrict__ wv_w,
                                           const float* __restrict__ wv_b,
                                           float* __restrict__ wqT,
                                           bf16* __restrict__ W2f,
                                           float* __restrict__ b2) {
    __shared__ __align__(16) unsigned char smem[16640];
    int tid = threadIdx.x;
    int blk = blockIdx.x;
    if (blk < 96) {
        // 64x64 tile transpose: tile (tc, td); 8 c-tiles x 12 d-tiles
        float (*tile)[65] = (float(*)[65])smem;
        int tc = blk & 7, td = blk >> 3;
        int c0 = tc * 64, d0 = td * 64;
        int row = tid >> 2, seg = tid & 3;
        const float* src = wq_w + (size_t)(c0 + row) * D_ + d0 + seg * 16;
        #pragma unroll
        for (int i = 0; i < 4; ++i) {
            f32x4 v = *(const f32x4*)(src + i * 4);
            tile[row][seg * 16 + i * 4 + 0] = v[0];
            tile[row][seg * 16 + i * 4 + 1] = v[1];
            tile[row][seg * 16 + i * 4 + 2] = v[2];
            tile[row][seg * 16 + i * 4 + 3] = v[3];
        }
        __syncthreads();
        float* dst = wqT + (size_t)(d0 + row) * C_ + c0 + seg * 16;
        #pragma unroll
        for (int i = 0; i < 4; ++i) {
            f32x4 v;
            v[0] = tile[seg * 16 + i * 4 + 0][row];
            v[1] = tile[seg * 16 + i * 4 + 1][row];
            v[2] = tile[seg * 16 + i * 4 + 2][row];
            v[3] = tile[seg * 16 + i * 4 + 3][row];
            *(f32x4*)(dst + i * 4) = v;
        }
    } else {
        int bb = blk - 96;                            // 0..511
        int og = bb >> 3, cc = bb & 7;                // 64 o-groups x 8 c-chunks
        int cl = tid & 63, kq = tid >> 6;             // wave = k-quarter
        int c  = cc * 64 + cl;
        const float* wo = wo_w + (size_t)og * 8 * C_; // uniform rows
        float a[8] = {};
        #pragma unroll 4
        for (int i = 0; i < 128; ++i) {
            int k = kq * 128 + i;
            float v = wv_w[(size_t)k * C_ + c];       // coalesced 256B/wave
            #pragma unroll
            for (int j = 0; j < 8; ++j)
                a[j] = fmaf(wo[(size_t)j * C_ + k], v, a[j]);  // s_load
        }
        float (*part)[8][64] = (float(*)[8][64])smem;
        #pragma unroll
        for (int j = 0; j < 8; ++j) part[kq][j][cl] = a[j];
        __syncthreads();
        if (kq == 0) {
            int t  = c >> 5;
            int ln = (((c >> 3) & 3) << 4);
            int el = c & 7;
            #pragma unroll
            for (int j = 0; j < 8; ++j) {
                float s = part[0][j][cl] + part[1][j][cl]
                        + part[2][j][cl] + part[3][j][cl];
                int o = og * 8 + j;
                W2f[(size_t)t * 16384 + (o >> 7) * 4096 + ((o >> 4) & 7) * 512
                    + (size_t)((o & 15) | ln) * 8 + el] = (bf16)s;
            }
        }
        if (cc == 0 && tid < 8) {
            float sb = 0.f;
            const float* rr = wo_w + (size_t)(og * 8 + tid) * C_;
            #pragma unroll 4
            for (int m = 0; m < C_; ++m) sb = fmaf(rr[m], wv_b[m], sb);
            b2[og * 8 + tid] = sb;
        }
    }
}

// ---------------------------------------------------------------------------
// K_q: Q[b,n,c] = weights[n] * sum_d se[b,n,d]*wqT[d,c] + wq_b[c]
// grid 128 = (16 b x 8 c-chunks); block 512 = (8 d-slices x 64 c).
// wqT coalesced (256B/wave), se via wave-uniform s_load, 8 n-accs/thread.
__global__ __launch_bounds__(512) void k_q(const float* __restrict__ se,
                                           const float* __restrict__ weights,
                                           const float* __restrict__ wqT,
                                           const float* __restrict__ wq_b,
                                           float* __restrict__ Q) {
    __shared__ float part[8][8][64];                  // 16KB
    int blk = blockIdx.x;
    int b = blk >> 3, ch = blk & 7;
    int cl = threadIdx.x & 63, ds = threadIdx.x >> 6; // ds = wave (0..7)
    int c = ch * 64 + cl;
    const float* seb = se + (size_t)b * N_ * D_ + ds * 96;  // uniform rows
    float a[8] = {};
    #pragma unroll 4
    for (int i = 0; i < 96; ++i) {
        float v = wqT[(size_t)(ds * 96 + i) * C_ + c];      // coalesced
        #pragma unroll
        for (int n = 0; n < 8; ++n)
            a[n] = fmaf(seb[(size_t)n * D_ + i], v, a[n]);  // s_load
    }
    #pragma unroll
    for (int n = 0; n < 8; ++n) part[ds][n][cl] = a[n];
    __syncthreads();
    if (ds == 0) {
        float qb = wq_b[c];
        #pragma unroll
        for (int n = 0; n < 8; ++n) {
            float s = 0.f;
            #pragma unroll
            for (int k = 0; k < 8; ++k) s += part[k][n][cl];
            Q[((size_t)b * N_ + n) * C_ + c] = weights[n] * s + qb;
        }
    }
}

// ---------------------------------------------------------------------------
// K_qk: Qkf[frag(b,n,m)] = bf16( (sum_o Q[b,n,o]*wk_w[o,m]) / sqrt(768) )
// grid 128 = (16 b x 8 m-chunks); block 512 = (8 o-slices x 64 m).
// wk_w coalesced, Q via wave-uniform s_load; zero-pads rows n+8.
__global__ __launch_bounds__(512) void k_qk(const float* __restrict__ Q,
                                            const float* __restrict__ wk_w,
                                            bf16* __restrict__ Qkf) {
    __shared__ float part[8][8][64];                  // 16KB
    int blk = blockIdx.x;
    int b = blk >> 3, mc = blk & 7;
    int ml = threadIdx.x & 63, os = threadIdx.x >> 6; // os = wave (0..7)
    int m = mc * 64 + ml;
    const float* qb = Q + (size_t)b * N_ * C_ + os * 64;    // uniform rows
    float a[8] = {};
    #pragma unroll 4
    for (int i = 0; i < 64; ++i) {
        float w = wk_w[(size_t)(os * 64 + i) * C_ + m];     // coalesced
        #pragma unroll
        for (int n = 0; n < 8; ++n)
            a[n] = fmaf(qb[(size_t)n * C_ + i], w, a[n]);   // s_load
    }
    #pragma unroll
    for (int n = 0; n < 8; ++n) part[os][n][ml] = a[n];
    __syncthreads();
    if (os == 0) {
        int t = m >> 5, sl = (m >> 3) & 3, el = m & 7;
        size_t base = (size_t)b * 8192 + (size_t)t * 512;
        #pragma unroll
        for (int n = 0; n < 8; ++n) {
            float s = 0.f;
            #pragma unroll
            for (int k = 0; k < 8; ++k) s += part[k][n][ml];
            Qkf[base + (size_t)(n | (sl << 4)) * 8 + el] =
                (bf16)(s * 3.6084391824351615e-2f);
            Qkf[base + (size_t)((n + 8) | (sl << 4)) * 8 + el] = (bf16)0.f;
        }
    }
}

// ---------------------------------------------------------------------------
// K2 (fused v6 — R12-exact control): per block (b, pt): full-M GEMM over
// 128-px panel. Bp persistent (128KB, swz; residual source); A fragments
// straight from W2f (fragment-order, coalesced, L2-hot); 16 tiles BK=32,
// one barrier per tile; B reg-staged 2 tiles ahead, static even/odd buffers.
__global__ __launch_bounds__(512, 2) void k_fused(const float* __restrict__ x,
                                                  const bf16* __restrict__ W2f,
                                                  const float* __restrict__ b2,
                                                  const float* __restrict__ wo_b,
                                                  const bf16* __restrict__ Qkf,
                                                  float* __restrict__ out) {
    // XCD swizzle (512 % 8 == 0 -> bijective)
    int id = blockIdx.x;
    int job = (id & 7) * 64 + (id >> 3);          // 0..511
    int b = job >> 5, pt = job & 31;
    int p0 = pt * 128;                            // 2 complete h-rows

    __shared__ __align__(128) unsigned char Bp[131072]; // [128 p][512 c] bf16 swz
    __shared__ float s_lds[128];

    int tid = threadIdx.x;
    int wid = tid >> 6, lane = tid & 63;
    int wm = wid >> 1, wp = wid & 1;

    int pg = tid & 127, cg = tid >> 7;            // B-stage: pixel, c-octet
    int fB = (pg & 63) << 4;

    f32x4 acc[8][4] = {};
    f32x4 acc_q[4] = {};

    const float* xb = x + (size_t)b * C_ * HW + p0 + pg;
    const bf16* Wb  = W2f + wm * 4096 + (size_t)lane * 8;
    const bf16* Qb  = Qkf + (size_t)b * 8192 + (size_t)lane * 8;

    float bvA[8], bvB[8];
    bf16x8 av[8];
    bf16x8 aq = {};

#define IB(T, BV)                                                             \
    { _Pragma("unroll")                                                       \
      for (int i = 0; i < 8; ++i)                                            \
          BV[i] = xb[(size_t)((T)*32 + cg*8 + i) * HW]; }

#define SW(T, BV)                                                             \
    { bf16x8 bw;                                                              \
      _Pragma("unroll")                                                       \
      for (int i = 0; i < 8; ++i) bw[i] = (bf16)BV[i];                        \
      *(bf16x8*)(&Bp[pg*1024 + ((((T)*64) + cg*16) ^ fB)]) = bw; }

#define IA(T)                                                                 \
    { _Pragma("unroll")                                                       \
      for (int i = 0; i < 8; ++i)                                            \
          av[i] = *(const bf16x8*)(Wb + (size_t)(T)*16384 + i*512);           \
      if (wm == 0) aq = *(const bf16x8*)(Qb + (size_t)(T)*512); }

#define MT(T)                                                                 \
    { int kb = (T)*64 + ((lane>>4)<<4);                                       \
      bf16x8 bbf[4];                                                          \
      _Pragma("unroll")                                                       \
      for (int j = 0; j < 4; ++j) {                                          \
          int row = wp*64 + j*16 + (lane&15);                                 \
          bbf[j] = *(const bf16x8*)(&Bp[row*1024 + (kb ^ ((row&63)<<4))]);    \
      }                                                                       \
      __builtin_amdgcn_s_setprio(1);                                          \
      _Pragma("unroll")                                                       \
      for (int i = 0; i < 8; ++i)                                            \
          _Pragma("unroll")                                                   \
          for (int j = 0; j < 4; ++j)                                        \
              acc[i][j] = __builtin_amdgcn_mfma_f32_16x16x32_bf16(            \
                              av[i], bbf[j], acc[i][j], 0, 0, 0);             \
      if (wm == 0) {                                                          \
          _Pragma("unroll")                                                   \
          for (int j = 0; j < 4; ++j)                                        \
              acc_q[j] = __builtin_amdgcn_mfma_f32_16x16x32_bf16(             \
                             aq, bbf[j], acc_q[j], 0, 0, 0);                  \
      }                                                                       \
      __builtin_amdgcn_s_setprio(0); }

    // ---- prologue: Bp(0) staged; B(1) in bvB, B(2) in flight to bvA ----
    IB(0, bvA); IB(1, bvB);
    SW(0, bvA);                                   // waits bvA loads
    IB(2, bvA);
    asm volatile("s_waitcnt lgkmcnt(0)" ::: "memory");
    __builtin_amdgcn_s_barrier();

    // ---- main loop: 16 tiles, 2 per iteration (static even/odd buffers) ----
    #pragma unroll 1
    for (int tt = 0; tt < 8; ++tt) {
        int t0 = tt * 2, t1 = t0 + 1;
        // tile t0 (even): stage odd tile t0+1 from bvB, refill bvB
        SW(t0 + 1, bvB);
        if (t0 + 3 <= 15) IB(t0 + 3, bvB);
        IA(t0);
        asm volatile("s_waitcnt lgkmcnt(0)" ::: "memory");
        __builtin_amdgcn_s_barrier();
        MT(t0);
        // tile t1 (odd): stage even tile t1+1 from bvA, refill bvA
        if (t1 + 1 <= 15) SW(t1 + 1, bvA);
        if (t1 + 3 <= 15) IB(t1 + 3, bvA);
        IA(t1);
        asm volatile("s_waitcnt lgkmcnt(0)" ::: "memory");
        __builtin_amdgcn_s_barrier();
        MT(t1);
    }

    // ---- in-register softmax over w (64 px) on waves 0,1 ----
    if (wm == 0) {
        float sm[4];
        #pragma unroll
        for (int r = 0; r < 4; ++r) {
            float m = fmaxf(fmaxf(acc_q[0][r], acc_q[1][r]),
                            fmaxf(acc_q[2][r], acc_q[3][r]));
            #pragma unroll
            for (int off = 1; off <= 8; off <<= 1) m = fmaxf(m, __shfl_xor(m, off));
            float s = 0.f;
            #pragma unroll
            for (int j = 0; j < 4; ++j) { acc_q[j][r] = __expf(acc_q[j][r] - m); s += acc_q[j][r]; }
            #pragma unroll
            for (int off = 1; off <= 8; off <<= 1) s += __shfl_xor(s, off);
            sm[r] = s;
        }
        f32x4 rcp;
        #pragma unroll
        for (int r = 0; r < 4; ++r) rcp[r] = 1.f / sm[r];
        #pragma unroll
        for (int j = 0; j < 4; ++j) {
            float sp = acc_q[j][0]*rcp[0] + acc_q[j][1]*rcp[1]
                     + acc_q[j][2]*rcp[2] + acc_q[j][3]*rcp[3];
            sp += __shfl_xor(sp, 16);             // add the other n-quad
            if (lane < 16) s_lds[wp*64 + j*16 + lane] = sp;
        }
    }
    __syncthreads();

    // ---- epilogue: out = bf16(x) + wo_b + s*(acc + b2); residual from Bp ----
    int r4 = (lane >> 4) << 2;
    int cl = lane & 15;
    #pragma unroll
    for (int j = 0; j < 4; ++j) {
        int pl = wp * 64 + j * 16 + cl;
        float sv = s_lds[pl];
        int fBp = (pl & 63) << 4;
        #pragma unroll
        for (int i = 0; i < 8; ++i) {
            int ob = wm * 128 + i * 16 + r4;
            f32x4 b2v = *(const f32x4*)(b2 + ob);
            f32x4 wbv = *(const f32x4*)(wo_b + ob);
            bf16x4 rx = *(const bf16x4*)(&Bp[pl*1024 + ((ob*2) ^ fBp)]);
            #pragma unroll
            for (int r = 0; r < 4; ++r) {
                size_t gi = ((size_t)b * C_ + ob + r) * HW + p0 + pl;
                out[gi] = (float)rx[r] + wbv[r] + sv * (acc[i][j][r] + b2v[r]);
            }
        }
    }
#undef IB
#undef SW
#undef IA
#undef MT
}

// ---------------------------------------------------------------------------
extern "C" void kernel_launch(void* const* d_in, const int* in_sizes, int n_in,
                              void* d_out, int out_size, void* d_ws, size_t ws_size,
                              hipStream_t stream) {
    const float* x    = (const float*)d_in[0];
    const float* se   = (const float*)d_in[1];
    const float* wts  = (const float*)d_in[2];
    const float* wq_w = (const float*)d_in[3];
    const float* wq_b = (const float*)d_in[4];
    const float* wk_w = (const float*)d_in[5];
    // d_in[6] = wk_b: constant over softmax axis -> cancels, unused
    const float* wv_w = (const float*)d_in[7];
    const float* wv_b = (const float*)d_in[8];
    const float* wo_w = (const float*)d_in[9];
    const float* wo_b = (const float*)d_in[10];
    float* out = (float*)d_out;

    // workspace layout (~2.6MB)
    char* ws = (char*)d_ws;
    bf16*  Qkf = (bf16*) (ws + 0);          // 256KB [16 b][16 t][64 lane][8]
    bf16*  W2f = (bf16*) (ws + 262144);     // 512KB [16 t][4 wm][8 i][64 lane][8]
    float* b2  = (float*)(ws + 786432);     // 2KB
    float* wqT = (float*)(ws + 790528);     // 1.5MB [768][512]
    float* Q   = (float*)(ws + 2363392);    // 256KB [16 b][8 n][512]

    k_w     <<<dim3(608), dim3(256), 0, stream>>>(wq_w, wo_w, wv_w, wv_b,
                                                  wqT, W2f, b2);
    k_q     <<<dim3(128), dim3(512), 0, stream>>>(se, wts, wqT, wq_b, Q);
    k_qk    <<<dim3(128), dim3(512), 0, stream>>>(Q, wk_w, Qkf);
    k_fused <<<dim3(512), dim3(512), 0, stream>>>(x, W2f, b2, wo_b, Qkf, out);
}